// Round 6
// baseline (172.193 us; speedup 1.0000x reference)
//
#include <hip/hip_runtime.h>
#include <hip/hip_bf16.h>

typedef __attribute__((ext_vector_type(8))) short short8;
typedef __attribute__((ext_vector_type(4))) float f32x4;
using u16 = unsigned short;
using u32 = unsigned int;

#define IN_F 4096
#define OUT_F 4096
#define RANK 128

// ---- bf16 pack helpers ----
__device__ inline u32 packi(int a, int b) {  // exact for [-8,7]
    float fa = (float)a, fb = (float)b;
    return (__builtin_bit_cast(u32, fa) >> 16) |
           (__builtin_bit_cast(u32, fb) & 0xFFFF0000u);
}
__device__ inline u32 packf(float a, float b) {  // RNE f32->bf16 pair
    u32 ua = __builtin_bit_cast(u32, a);
    u32 ub = __builtin_bit_cast(u32, b);
    ua = (ua + 0x7FFFu + ((ua >> 16) & 1u)) >> 16;
    ub = (ub + 0x7FFFu + ((ub >> 16) & 1u));
    return ua | (ub & 0xFFFF0000u);
}
__device__ inline u16 f2bf(float f) {
    u32 u = __builtin_bit_cast(u32, f);
    u = (u + 0x7FFFu + ((u >> 16) & 1u)) >> 16;
    return (u16)u;
}

// ws: y 64KB | yp 1MB | xb 1MB | bt 1MB | at 1MB | part 8MB  (~12.3MB)
#define WS_Y 0
#define WS_YP 65536
#define WS_XB (WS_YP + 1048576)
#define WS_BT (WS_XB + 1048576)
#define WS_AT (WS_BT + 1048576)
#define WS_PART (WS_AT + 1048576)

// ---- prep1: [0,128) x->bf16 | [128,384) A^T->at | [384,640) B^T->bt
__global__ __launch_bounds__(512) void prep1_kernel(
    const float* __restrict__ x, const float* __restrict__ A,
    const float* __restrict__ B, u16* __restrict__ xb,
    u16* __restrict__ at, u16* __restrict__ bt) {
    __shared__ float tile[64 * 33];
    int bid = blockIdx.x, tid = threadIdx.x;
    if (bid < 128) {
        const f32x4* xv = (const f32x4*)x;
        int vi = bid * 1024 + tid * 2;
        f32x4 a = xv[vi], b = xv[vi + 1];
        union { u32 u[4]; short8 s; } p;
        p.u[0] = packf(a[0], a[1]); p.u[1] = packf(a[2], a[3]);
        p.u[2] = packf(b[0], b[1]); p.u[3] = packf(b[2], b[3]);
        *(short8*)(xb + (size_t)vi * 4) = p.s;
    } else if (bid < 384) {
        int b2 = bid - 128, kt = b2 >> 2, rt = b2 & 3;
        int k0 = kt * 64, r0 = rt * 32;
        for (int u = tid; u < 2048; u += 512) {
            int row = u >> 5, c = u & 31;
            tile[row * 33 + c] = A[(size_t)(k0 + row) * RANK + r0 + c];
        }
        __syncthreads();
        for (int u = tid; u < 2048; u += 512) {
            int rr = u >> 6, k = u & 63;
            at[(size_t)(r0 + rr) * IN_F + k0 + k] = f2bf(tile[k * 33 + rr]);
        }
    } else {
        int b2 = bid - 384, rt = b2 >> 7, ot = b2 & 127;
        int r0 = rt * 64, o0 = ot * 32;
        for (int u = tid; u < 2048; u += 512) {
            int row = u >> 5, c = u & 31;
            tile[row * 33 + c] = B[(size_t)(r0 + row) * OUT_F + o0 + c];
        }
        __syncthreads();
        for (int u = tid; u < 2048; u += 512) {
            int oo = u >> 6, k = u & 63;
            bt[(size_t)(o0 + oo) * RANK + r0 + k] = f2bf(tile[k * 33 + oo]);
        }
    }
}

// ---- prep2: yp[kq][m][r] = partial of xb @ at^T (64 blocks, NO atomics)
__global__ __launch_bounds__(512) void prep2_kernel(
    const u16* __restrict__ xb, const u16* __restrict__ at,
    float* __restrict__ yp) {
    int tid = threadIdx.x, lane = tid & 63, wid = tid >> 6;
    int wm = wid >> 1, wn = wid & 1;
    int col = lane & 15, kg = lane >> 4;
    int rt = blockIdx.x & 3, kq = blockIdx.x >> 2;
    int r = rt * 32 + wn * 16 + col;
    int k0 = kq * 256;
    const u16* xp0 = xb + (size_t)(wm * 32 + col) * IN_F + k0 + kg * 8;
    const u16* xp1 = xp0 + (size_t)16 * IN_F;
    const u16* ap = at + (size_t)r * IN_F + k0 + kg * 8;
    f32x4 acc0 = {0.f, 0.f, 0.f, 0.f}, acc1 = {0.f, 0.f, 0.f, 0.f};
    #pragma unroll
    for (int k = 0; k < 256; k += 32) {
        short8 bf = *(const short8*)(ap + k);
        short8 a0 = *(const short8*)(xp0 + k);
        short8 a1 = *(const short8*)(xp1 + k);
        acc0 = __builtin_amdgcn_mfma_f32_16x16x32_bf16(a0, bf, acc0, 0, 0, 0);
        acc1 = __builtin_amdgcn_mfma_f32_16x16x32_bf16(a1, bf, acc1, 0, 0, 0);
    }
    int rbase = wm * 32 + kg * 4;
    float* yq = yp + (size_t)kq * 128 * RANK;
    #pragma unroll
    for (int j = 0; j < 4; ++j) {
        yq[(rbase + j) * RANK + r] = acc0[j];
        yq[(rbase + j + 16) * RANK + r] = acc1[j];
    }
}

// ---- reduce_y: y = sum over 16 kq slices (8 blocks x 512)
__global__ __launch_bounds__(512) void reduce_y_kernel(
    const float* __restrict__ yp, float* __restrict__ y) {
    int idx = blockIdx.x * 512 + threadIdx.x;  // 4096 f32x4
    const f32x4* v = (const f32x4*)yp;
    f32x4 s = {0.f, 0.f, 0.f, 0.f};
    #pragma unroll
    for (int kq = 0; kq < 16; ++kq) {
        f32x4 t = v[kq * 4096 + idx];
        s[0] += t[0]; s[1] += t[1]; s[2] += t[2]; s[3] += t[3];
    }
    ((f32x4*)y)[idx] = s;
}

// ---- main: BM=64, BN=64, ksplit=4 -> 512 blocks x 8 waves. NO atomics:
// each kq writes its own part[kq][128][4096] slice; kq==0 adds lora+bias.
#define KCHUNK 1024
__global__ __launch_bounds__(512, 4) void main_kernel(
    const u16* __restrict__ xb, const int* __restrict__ wq,
    const float* __restrict__ scale, const float* __restrict__ bias,
    const float* __restrict__ y, const u16* __restrict__ bt,
    float* __restrict__ part) {
    int tid = threadIdx.x, lane = tid & 63, wid = tid >> 6;
    int wm = wid >> 2, wn = wid & 3;
    int col = lane & 15, kg = lane >> 4;
    int bid = blockIdx.x;
    int ot = bid & 63, mt = (bid >> 6) & 1, kq = bid >> 7;
    int o = ot * 64 + wn * 16 + col;
    int m0 = mt * 64 + wm * 32 + col;
    int k0 = kq * KCHUNK;

    const int* wp = wq + (size_t)o * IN_F + k0 + kg * 8;
    const u16* xp0 = xb + (size_t)m0 * IN_F + k0 + kg * 8;
    const u16* xp1 = xp0 + (size_t)16 * IN_F;

    f32x4 acc0 = {0.f, 0.f, 0.f, 0.f}, acc1 = {0.f, 0.f, 0.f, 0.f};
    #pragma unroll 4
    for (int it = 0; it < 32; ++it) {
        int4 wa = *(const int4*)(wp + it * 32);
        int4 wb = *(const int4*)(wp + it * 32 + 4);
        short8 a0 = *(const short8*)(xp0 + it * 32);
        short8 a1 = *(const short8*)(xp1 + it * 32);
        union { u32 u[4]; short8 s; } bf;
        bf.u[0] = packi(wa.x, wa.y); bf.u[1] = packi(wa.z, wa.w);
        bf.u[2] = packi(wb.x, wb.y); bf.u[3] = packi(wb.z, wb.w);
        acc0 = __builtin_amdgcn_mfma_f32_16x16x32_bf16(a0, bf.s, acc0, 0, 0, 0);
        acc1 = __builtin_amdgcn_mfma_f32_16x16x32_bf16(a1, bf.s, acc1, 0, 0, 0);
    }

    float s = scale[o];
    #pragma unroll
    for (int j = 0; j < 4; ++j) { acc0[j] *= s; acc1[j] *= s; }

    if (kq == 0) {  // LoRA + bias folded into slice 0
        const float* yp0 = y + (size_t)m0 * RANK + kg * 8;
        const float* yp1 = yp0 + 16 * RANK;
        const u16* bp = bt + (size_t)o * RANK + kg * 8;
        #pragma unroll
        for (int ks = 0; ks < RANK; ks += 32) {
            f32x4 ya = *(const f32x4*)(yp0 + ks);
            f32x4 yb = *(const f32x4*)(yp0 + ks + 4);
            f32x4 yc = *(const f32x4*)(yp1 + ks);
            f32x4 yd = *(const f32x4*)(yp1 + ks + 4);
            union { u32 u[4]; short8 s; } af0, af1;
            af0.u[0] = packf(ya[0], ya[1]); af0.u[1] = packf(ya[2], ya[3]);
            af0.u[2] = packf(yb[0], yb[1]); af0.u[3] = packf(yb[2], yb[3]);
            af1.u[0] = packf(yc[0], yc[1]); af1.u[1] = packf(yc[2], yc[3]);
            af1.u[2] = packf(yd[0], yd[1]); af1.u[3] = packf(yd[2], yd[3]);
            short8 bfr = *(const short8*)(bp + ks);
            acc0 = __builtin_amdgcn_mfma_f32_16x16x32_bf16(af0.s, bfr, acc0, 0, 0, 0);
            acc1 = __builtin_amdgcn_mfma_f32_16x16x32_bf16(af1.s, bfr, acc1, 0, 0, 0);
        }
        float bv = bias[o];
        #pragma unroll
        for (int j = 0; j < 4; ++j) { acc0[j] += bv; acc1[j] += bv; }
    }

    int rbase = mt * 64 + wm * 32 + kg * 4;
    float* op = part + (size_t)kq * 128 * OUT_F + (size_t)rbase * OUT_F + o;
    #pragma unroll
    for (int j = 0; j < 4; ++j) {
        op[(size_t)j * OUT_F] = acc0[j];
        op[(size_t)(j + 16) * OUT_F] = acc1[j];
    }
}

// ---- reduce_out: out = part0+part1+part2+part3 (256 blocks x 512)
__global__ __launch_bounds__(512) void reduce_out_kernel(
    const float* __restrict__ part, float* __restrict__ out) {
    const f32x4* p0 = (const f32x4*)part;
    const f32x4* p1 = p0 + 131072;
    const f32x4* p2 = p1 + 131072;
    const f32x4* p3 = p2 + 131072;
    f32x4* ov = (f32x4*)out;
    int idx = blockIdx.x * 512 + threadIdx.x;  // 131072 threads x 1
    f32x4 a = p0[idx], b = p1[idx], c = p2[idx], d = p3[idx];
    f32x4 s;
    #pragma unroll
    for (int j = 0; j < 4; ++j) s[j] = (a[j] + b[j]) + (c[j] + d[j]);
    ov[idx] = s;
}

extern "C" void kernel_launch(void* const* d_in, const int* in_sizes, int n_in,
                              void* d_out, int out_size, void* d_ws, size_t ws_size,
                              hipStream_t stream) {
    const float* x = (const float*)d_in[0];
    const int* wq = (const int*)d_in[1];
    const float* scale = (const float*)d_in[2];
    const float* A = (const float*)d_in[3];
    const float* B = (const float*)d_in[4];
    const float* bias = (const float*)d_in[5];
    float* out = (float*)d_out;

    char* ws = (char*)d_ws;
    float* y = (float*)(ws + WS_Y);
    float* yp = (float*)(ws + WS_YP);
    u16* xb = (u16*)(ws + WS_XB);
    u16* bt = (u16*)(ws + WS_BT);
    u16* at = (u16*)(ws + WS_AT);
    float* part = (float*)(ws + WS_PART);

    prep1_kernel<<<640, 512, 0, stream>>>(x, A, B, xb, at, bt);
    prep2_kernel<<<64, 512, 0, stream>>>(xb, at, yp);
    reduce_y_kernel<<<8, 512, 0, stream>>>(yp, y);
    main_kernel<<<512, 512, 0, stream>>>(xb, wq, scale, bias, y, bt, part);
    reduce_out_kernel<<<256, 512, 0, stream>>>(part, out);
}

// Round 9
// 171.496 us; speedup vs baseline: 1.0041x; 1.0041x over previous
//
#include <hip/hip_runtime.h>
#include <hip/hip_bf16.h>

typedef __attribute__((ext_vector_type(8))) short short8;
typedef __attribute__((ext_vector_type(4))) float f32x4;
using u16 = unsigned short;
using u32 = unsigned int;

#define IN_F 4096
#define OUT_F 4096
#define RANK 128

// ---- bf16 pack helpers ----
__device__ inline u32 packi(int a, int b) {  // exact for [-8,7]
    float fa = (float)a, fb = (float)b;
    return (__builtin_bit_cast(u32, fa) >> 16) |
           (__builtin_bit_cast(u32, fb) & 0xFFFF0000u);
}
__device__ inline u32 packf(float a, float b) {  // RNE f32->bf16 pair
    u32 ua = __builtin_bit_cast(u32, a);
    u32 ub = __builtin_bit_cast(u32, b);
    ua = (ua + 0x7FFFu + ((ua >> 16) & 1u)) >> 16;
    ub = (ub + 0x7FFFu + ((ub >> 16) & 1u));
    return ua | (ub & 0xFFFF0000u);
}
__device__ inline u16 f2bf(float f) {
    u32 u = __builtin_bit_cast(u32, f);
    u = (u + 0x7FFFu + ((u >> 16) & 1u)) >> 16;
    return (u16)u;
}

// ws: y 64KB | yp 1MB | xb 1MB | bt 1MB | at 1MB | part 8MB
#define WS_Y 0
#define WS_YP 65536
#define WS_XB (WS_YP + 1048576)
#define WS_BT (WS_XB + 1048576)
#define WS_AT (WS_BT + 1048576)
#define WS_PART (WS_AT + 1048576)

// ---- prep1: [0,128) x->bf16 | [128,384) A^T->at | [384,640) B^T->bt
__global__ __launch_bounds__(512) void prep1_kernel(
    const float* __restrict__ x, const float* __restrict__ A,
    const float* __restrict__ B, u16* __restrict__ xb,
    u16* __restrict__ at, u16* __restrict__ bt) {
    __shared__ float tile[64 * 33];
    int bid = blockIdx.x, tid = threadIdx.x;
    if (bid < 128) {
        const f32x4* xv = (const f32x4*)x;
        int vi = bid * 1024 + tid * 2;
        f32x4 a = xv[vi], b = xv[vi + 1];
        union { u32 u[4]; short8 s; } p;
        p.u[0] = packf(a[0], a[1]); p.u[1] = packf(a[2], a[3]);
        p.u[2] = packf(b[0], b[1]); p.u[3] = packf(b[2], b[3]);
        *(short8*)(xb + (size_t)vi * 4) = p.s;
    } else if (bid < 384) {
        int b2 = bid - 128, kt = b2 >> 2, rt = b2 & 3;
        int k0 = kt * 64, r0 = rt * 32;
        for (int u = tid; u < 2048; u += 512) {
            int row = u >> 5, c = u & 31;
            tile[row * 33 + c] = A[(size_t)(k0 + row) * RANK + r0 + c];
        }
        __syncthreads();
        for (int u = tid; u < 2048; u += 512) {
            int rr = u >> 6, k = u & 63;
            at[(size_t)(r0 + rr) * IN_F + k0 + k] = f2bf(tile[k * 33 + rr]);
        }
    } else {
        int b2 = bid - 384, rt = b2 >> 7, ot = b2 & 127;
        int r0 = rt * 64, o0 = ot * 32;
        for (int u = tid; u < 2048; u += 512) {
            int row = u >> 5, c = u & 31;
            tile[row * 33 + c] = B[(size_t)(r0 + row) * OUT_F + o0 + c];
        }
        __syncthreads();
        for (int u = tid; u < 2048; u += 512) {
            int oo = u >> 6, k = u & 63;
            bt[(size_t)(o0 + oo) * RANK + r0 + k] = f2bf(tile[k * 33 + oo]);
        }
    }
}

// ---- prep2: yp[kq][m][r] = partial of xb @ at^T (64 blocks, no atomics)
__global__ __launch_bounds__(512) void prep2_kernel(
    const u16* __restrict__ xb, const u16* __restrict__ at,
    float* __restrict__ yp) {
    int tid = threadIdx.x, lane = tid & 63, wid = tid >> 6;
    int wm = wid >> 1, wn = wid & 1;
    int col = lane & 15, kg = lane >> 4;
    int rt = blockIdx.x & 3, kq = blockIdx.x >> 2;
    int r = rt * 32 + wn * 16 + col;
    int k0 = kq * 256;
    const u16* xp0 = xb + (size_t)(wm * 32 + col) * IN_F + k0 + kg * 8;
    const u16* xp1 = xp0 + (size_t)16 * IN_F;
    const u16* ap = at + (size_t)r * IN_F + k0 + kg * 8;
    f32x4 acc0 = {0.f, 0.f, 0.f, 0.f}, acc1 = {0.f, 0.f, 0.f, 0.f};
    #pragma unroll
    for (int k = 0; k < 256; k += 32) {
        short8 bf = *(const short8*)(ap + k);
        short8 a0 = *(const short8*)(xp0 + k);
        short8 a1 = *(const short8*)(xp1 + k);
        acc0 = __builtin_amdgcn_mfma_f32_16x16x32_bf16(a0, bf, acc0, 0, 0, 0);
        acc1 = __builtin_amdgcn_mfma_f32_16x16x32_bf16(a1, bf, acc1, 0, 0, 0);
    }
    int rbase = wm * 32 + kg * 4;
    float* yq = yp + (size_t)kq * 128 * RANK;
    #pragma unroll
    for (int j = 0; j < 4; ++j) {
        yq[(rbase + j) * RANK + r] = acc0[j];
        yq[(rbase + j + 16) * RANK + r] = acc1[j];
    }
}

// ---- reduce_y: y = sum of 16 kq slices
__global__ __launch_bounds__(512) void reduce_y_kernel(
    const float* __restrict__ yp, float* __restrict__ y) {
    int idx = blockIdx.x * 512 + threadIdx.x;
    const f32x4* v = (const f32x4*)yp;
    f32x4 s = {0.f, 0.f, 0.f, 0.f};
    #pragma unroll
    for (int kq = 0; kq < 16; ++kq) {
        f32x4 t = v[kq * 4096 + idx];
        s[0] += t[0]; s[1] += t[1]; s[2] += t[2]; s[3] += t[3];
    }
    ((f32x4*)y)[idx] = s;
}

// ---- main: BM=64, BN=64, ksplit=4 -> 512 blocks x 8 waves.
// Explicit double-bank register pipeline (bank = 2 K-steps = 8 loads),
// sched_barrier(0) pins load/compute batches so loads stay in flight.
#define KCHUNK 1024
#define SBAR __builtin_amdgcn_sched_barrier(0)

#define LOADB(P, it) \
    wa0##P = *(const int4*)(wp + (it) * 32); \
    wb0##P = *(const int4*)(wp + (it) * 32 + 4); \
    x00##P = *(const short8*)(xp0 + (it) * 32); \
    x10##P = *(const short8*)(xp1 + (it) * 32); \
    wa1##P = *(const int4*)(wp + (it) * 32 + 32); \
    wb1##P = *(const int4*)(wp + (it) * 32 + 36); \
    x01##P = *(const short8*)(xp0 + (it) * 32 + 32); \
    x11##P = *(const short8*)(xp1 + (it) * 32 + 32);

#define COMPB(P) { \
    union { u32 u[4]; short8 s; } bf; \
    bf.u[0] = packi(wa0##P.x, wa0##P.y); bf.u[1] = packi(wa0##P.z, wa0##P.w); \
    bf.u[2] = packi(wb0##P.x, wb0##P.y); bf.u[3] = packi(wb0##P.z, wb0##P.w); \
    acc0 = __builtin_amdgcn_mfma_f32_16x16x32_bf16(x00##P, bf.s, acc0, 0, 0, 0); \
    acc1 = __builtin_amdgcn_mfma_f32_16x16x32_bf16(x10##P, bf.s, acc1, 0, 0, 0); \
    bf.u[0] = packi(wa1##P.x, wa1##P.y); bf.u[1] = packi(wa1##P.z, wa1##P.w); \
    bf.u[2] = packi(wb1##P.x, wb1##P.y); bf.u[3] = packi(wb1##P.z, wb1##P.w); \
    acc0 = __builtin_amdgcn_mfma_f32_16x16x32_bf16(x01##P, bf.s, acc0, 0, 0, 0); \
    acc1 = __builtin_amdgcn_mfma_f32_16x16x32_bf16(x11##P, bf.s, acc1, 0, 0, 0); }

__global__ __launch_bounds__(512, 4) void main_kernel(
    const u16* __restrict__ xb, const int* __restrict__ wq,
    const float* __restrict__ scale, const float* __restrict__ bias,
    const float* __restrict__ y, const u16* __restrict__ bt,
    float* __restrict__ part) {
    int tid = threadIdx.x, lane = tid & 63, wid = tid >> 6;
    int wm = wid >> 2, wn = wid & 3;
    int col = lane & 15, kg = lane >> 4;
    int bid = blockIdx.x;
    int ot = bid & 63, mt = (bid >> 6) & 1, kq = bid >> 7;
    int o = ot * 64 + wn * 16 + col;
    int m0 = mt * 64 + wm * 32 + col;
    int k0 = kq * KCHUNK;

    const int* wp = wq + (size_t)o * IN_F + k0 + kg * 8;
    const u16* xp0 = xb + (size_t)m0 * IN_F + k0 + kg * 8;
    const u16* xp1 = xp0 + (size_t)16 * IN_F;

    f32x4 acc0 = {0.f, 0.f, 0.f, 0.f}, acc1 = {0.f, 0.f, 0.f, 0.f};

    int4 wa0A, wb0A, wa1A, wb1A, wa0B, wb0B, wa1B, wb1B;
    short8 x00A, x10A, x01A, x11A, x00B, x10B, x01B, x11B;

    LOADB(A, 0)
    LOADB(B, 2)
    SBAR;
    #pragma unroll
    for (int s = 4; s <= 28; s += 4) {
        COMPB(A) LOADB(A, s) SBAR;
        COMPB(B) LOADB(B, s + 2) SBAR;
    }
    COMPB(A)
    COMPB(B)

    float s = scale[o];
    #pragma unroll
    for (int j = 0; j < 4; ++j) { acc0[j] *= s; acc1[j] *= s; }

    if (kq == 0) {  // LoRA + bias folded into slice 0
        const float* yp0 = y + (size_t)m0 * RANK + kg * 8;
        const float* yp1 = yp0 + 16 * RANK;
        const u16* bp = bt + (size_t)o * RANK + kg * 8;
        #pragma unroll
        for (int ks = 0; ks < RANK; ks += 32) {
            f32x4 ya = *(const f32x4*)(yp0 + ks);
            f32x4 yb = *(const f32x4*)(yp0 + ks + 4);
            f32x4 yc = *(const f32x4*)(yp1 + ks);
            f32x4 yd = *(const f32x4*)(yp1 + ks + 4);
            union { u32 u[4]; short8 s; } af0, af1;
            af0.u[0] = packf(ya[0], ya[1]); af0.u[1] = packf(ya[2], ya[3]);
            af0.u[2] = packf(yb[0], yb[1]); af0.u[3] = packf(yb[2], yb[3]);
            af1.u[0] = packf(yc[0], yc[1]); af1.u[1] = packf(yc[2], yc[3]);
            af1.u[2] = packf(yd[0], yd[1]); af1.u[3] = packf(yd[2], yd[3]);
            short8 bfr = *(const short8*)(bp + ks);
            acc0 = __builtin_amdgcn_mfma_f32_16x16x32_bf16(af0.s, bfr, acc0, 0, 0, 0);
            acc1 = __builtin_amdgcn_mfma_f32_16x16x32_bf16(af1.s, bfr, acc1, 0, 0, 0);
        }
        float bv = bias[o];
        #pragma unroll
        for (int j = 0; j < 4; ++j) { acc0[j] += bv; acc1[j] += bv; }
    }

    int rbase = mt * 64 + wm * 32 + kg * 4;
    float* op = part + (size_t)kq * 128 * OUT_F + (size_t)rbase * OUT_F + o;
    #pragma unroll
    for (int j = 0; j < 4; ++j) {
        op[(size_t)j * OUT_F] = acc0[j];
        op[(size_t)(j + 16) * OUT_F] = acc1[j];
    }
}

// ---- reduce_out: out = part0+..+part3
__global__ __launch_bounds__(512) void reduce_out_kernel(
    const float* __restrict__ part, float* __restrict__ out) {
    const f32x4* p0 = (const f32x4*)part;
    const f32x4* p1 = p0 + 131072;
    const f32x4* p2 = p1 + 131072;
    const f32x4* p3 = p2 + 131072;
    f32x4* ov = (f32x4*)out;
    int idx = blockIdx.x * 512 + threadIdx.x;
    f32x4 a = p0[idx], b = p1[idx], c = p2[idx], d = p3[idx];
    f32x4 s;
    #pragma unroll
    for (int j = 0; j < 4; ++j) s[j] = (a[j] + b[j]) + (c[j] + d[j]);
    ov[idx] = s;
}

extern "C" void kernel_launch(void* const* d_in, const int* in_sizes, int n_in,
                              void* d_out, int out_size, void* d_ws, size_t ws_size,
                              hipStream_t stream) {
    const float* x = (const float*)d_in[0];
    const int* wq = (const int*)d_in[1];
    const float* scale = (const float*)d_in[2];
    const float* A = (const float*)d_in[3];
    const float* B = (const float*)d_in[4];
    const float* bias = (const float*)d_in[5];
    float* out = (float*)d_out;

    char* ws = (char*)d_ws;
    float* y = (float*)(ws + WS_Y);
    float* yp = (float*)(ws + WS_YP);
    u16* xb = (u16*)(ws + WS_XB);
    u16* bt = (u16*)(ws + WS_BT);
    u16* at = (u16*)(ws + WS_AT);
    float* part = (float*)(ws + WS_PART);

    prep1_kernel<<<640, 512, 0, stream>>>(x, A, B, xb, at, bt);
    prep2_kernel<<<64, 512, 0, stream>>>(xb, at, yp);
    reduce_y_kernel<<<8, 512, 0, stream>>>(yp, y);
    main_kernel<<<512, 512, 0, stream>>>(xb, wq, scale, bias, y, bt, part);
    reduce_out_kernel<<<256, 512, 0, stream>>>(part, out);
}

// Round 10
// 152.531 us; speedup vs baseline: 1.1289x; 1.1243x over previous
//
#include <hip/hip_runtime.h>
#include <hip/hip_bf16.h>

typedef __attribute__((ext_vector_type(8))) short short8;
typedef __attribute__((ext_vector_type(4))) float f32x4;
using u16 = unsigned short;
using u32 = unsigned int;

#define IN_F 4096
#define OUT_F 4096
#define RANK 128

typedef const __attribute__((address_space(1))) int* gas_ptr;
typedef __attribute__((address_space(3))) int* las_ptr;

// ---- bf16 pack helpers ----
__device__ inline u32 packi(int a, int b) {  // exact for [-8,7]
    float fa = (float)a, fb = (float)b;
    return (__builtin_bit_cast(u32, fa) >> 16) |
           (__builtin_bit_cast(u32, fb) & 0xFFFF0000u);
}
__device__ inline u32 packf(float a, float b) {  // RNE f32->bf16 pair
    u32 ua = __builtin_bit_cast(u32, a);
    u32 ub = __builtin_bit_cast(u32, b);
    ua = (ua + 0x7FFFu + ((ua >> 16) & 1u)) >> 16;
    ub = (ub + 0x7FFFu + ((ub >> 16) & 1u));
    return ua | (ub & 0xFFFF0000u);
}
__device__ inline u16 f2bf(float f) {
    u32 u = __builtin_bit_cast(u32, f);
    u = (u + 0x7FFFu + ((u >> 16) & 1u)) >> 16;
    return (u16)u;
}

// ws: y 64KB | yp 1MB | xb 1MB | bt 1MB | at 1MB | part 8MB
#define WS_Y 0
#define WS_YP 65536
#define WS_XB (WS_YP + 1048576)
#define WS_BT (WS_XB + 1048576)
#define WS_AT (WS_BT + 1048576)
#define WS_PART (WS_AT + 1048576)

// ---- prep1: [0,128) x->bf16 | [128,384) A^T->at | [384,640) B^T->bt
__global__ __launch_bounds__(512) void prep1_kernel(
    const float* __restrict__ x, const float* __restrict__ A,
    const float* __restrict__ B, u16* __restrict__ xb,
    u16* __restrict__ at, u16* __restrict__ bt) {
    __shared__ float tile[64 * 33];
    int bid = blockIdx.x, tid = threadIdx.x;
    if (bid < 128) {
        const f32x4* xv = (const f32x4*)x;
        int vi = bid * 1024 + tid * 2;
        f32x4 a = xv[vi], b = xv[vi + 1];
        union { u32 u[4]; short8 s; } p;
        p.u[0] = packf(a[0], a[1]); p.u[1] = packf(a[2], a[3]);
        p.u[2] = packf(b[0], b[1]); p.u[3] = packf(b[2], b[3]);
        *(short8*)(xb + (size_t)vi * 4) = p.s;
    } else if (bid < 384) {
        int b2 = bid - 128, kt = b2 >> 2, rt = b2 & 3;
        int k0 = kt * 64, r0 = rt * 32;
        for (int u = tid; u < 2048; u += 512) {
            int row = u >> 5, c = u & 31;
            tile[row * 33 + c] = A[(size_t)(k0 + row) * RANK + r0 + c];
        }
        __syncthreads();
        for (int u = tid; u < 2048; u += 512) {
            int rr = u >> 6, k = u & 63;
            at[(size_t)(r0 + rr) * IN_F + k0 + k] = f2bf(tile[k * 33 + rr]);
        }
    } else {
        int b2 = bid - 384, rt = b2 >> 7, ot = b2 & 127;
        int r0 = rt * 64, o0 = ot * 32;
        for (int u = tid; u < 2048; u += 512) {
            int row = u >> 5, c = u & 31;
            tile[row * 33 + c] = B[(size_t)(r0 + row) * OUT_F + o0 + c];
        }
        __syncthreads();
        for (int u = tid; u < 2048; u += 512) {
            int oo = u >> 6, k = u & 63;
            bt[(size_t)(o0 + oo) * RANK + r0 + k] = f2bf(tile[k * 33 + oo]);
        }
    }
}

// ---- prep2: yp[kq][m][r] = partial of xb @ at^T
__global__ __launch_bounds__(512) void prep2_kernel(
    const u16* __restrict__ xb, const u16* __restrict__ at,
    float* __restrict__ yp) {
    int tid = threadIdx.x, lane = tid & 63, wid = tid >> 6;
    int wm = wid >> 1, wn = wid & 1;
    int col = lane & 15, kg = lane >> 4;
    int rt = blockIdx.x & 3, kq = blockIdx.x >> 2;
    int r = rt * 32 + wn * 16 + col;
    int k0 = kq * 256;
    const u16* xp0 = xb + (size_t)(wm * 32 + col) * IN_F + k0 + kg * 8;
    const u16* xp1 = xp0 + (size_t)16 * IN_F;
    const u16* ap = at + (size_t)r * IN_F + k0 + kg * 8;
    f32x4 acc0 = {0.f, 0.f, 0.f, 0.f}, acc1 = {0.f, 0.f, 0.f, 0.f};
    #pragma unroll
    for (int k = 0; k < 256; k += 32) {
        short8 bf = *(const short8*)(ap + k);
        short8 a0 = *(const short8*)(xp0 + k);
        short8 a1 = *(const short8*)(xp1 + k);
        acc0 = __builtin_amdgcn_mfma_f32_16x16x32_bf16(a0, bf, acc0, 0, 0, 0);
        acc1 = __builtin_amdgcn_mfma_f32_16x16x32_bf16(a1, bf, acc1, 0, 0, 0);
    }
    int rbase = wm * 32 + kg * 4;
    float* yq = yp + (size_t)kq * 128 * RANK;
    #pragma unroll
    for (int j = 0; j < 4; ++j) {
        yq[(rbase + j) * RANK + r] = acc0[j];
        yq[(rbase + j + 16) * RANK + r] = acc1[j];
    }
}

// ---- reduce_y
__global__ __launch_bounds__(512) void reduce_y_kernel(
    const float* __restrict__ yp, float* __restrict__ y) {
    int idx = blockIdx.x * 512 + threadIdx.x;
    const f32x4* v = (const f32x4*)yp;
    f32x4 s = {0.f, 0.f, 0.f, 0.f};
    #pragma unroll
    for (int kq = 0; kq < 16; ++kq) {
        f32x4 t = v[kq * 4096 + idx];
        s[0] += t[0]; s[1] += t[1]; s[2] += t[2]; s[3] += t[3];
    }
    ((f32x4*)y)[idx] = s;
}

// ---- main: BM=64, BN=64, ksplit=4 -> 512 blocks x 8 waves (2 blocks/CU).
// wq: 3-buffer LDS pipeline via global_load_lds (swizzled), counted vmcnt(6),
// raw s_barrier (NO __syncthreads -> no vmcnt(0) drain). x: inline-asm
// dwordx4 into double-banked "=v" regs (opaque to compiler waitcnt).
#define NT 16

#define XLOAD(P, tn) { \
    const u16* _a = xp0 + (tn) * 64; \
    const u16* _b = xp1 + (tn) * 64; \
    asm volatile("global_load_dwordx4 %0, %1, off" : "=v"(x00##P) : "v"(_a)); \
    asm volatile("global_load_dwordx4 %0, %1, off" : "=v"(x01##P) : "v"(_a + 32)); \
    asm volatile("global_load_dwordx4 %0, %1, off" : "=v"(x10##P) : "v"(_b)); \
    asm volatile("global_load_dwordx4 %0, %1, off" : "=v"(x11##P) : "v"(_b + 32)); }

#define STAGE(buf, tt) { \
    __builtin_amdgcn_global_load_lds((gas_ptr)(sp1 + (tt) * 64), \
        (las_ptr)&lds[buf][wid * 256], 16, 0, 0); \
    __builtin_amdgcn_global_load_lds((gas_ptr)(sp2 + (tt) * 64), \
        (las_ptr)&lds[buf][2048 + wid * 256], 16, 0, 0); }

#define WAITB { \
    asm volatile("s_waitcnt vmcnt(6)" ::: "memory"); \
    __builtin_amdgcn_sched_barrier(0); \
    __builtin_amdgcn_s_barrier(); \
    __builtin_amdgcn_sched_barrier(0); }

#define COMPUTE(P, t) { \
    const char* bb = ldsb + ((t) % 3) * 16384 + rbyte; \
    int4 wa0 = *(const int4*)(bb + ((kg * 32) ^ bx)); \
    int4 wa1 = *(const int4*)(bb + ((kg * 32 + 16) ^ bx)); \
    int4 wb0 = *(const int4*)(bb + ((kg * 32 + 128) ^ bx)); \
    int4 wb1 = *(const int4*)(bb + ((kg * 32 + 144) ^ bx)); \
    union { u32 u[4]; short8 s; } f0, f1; \
    f0.u[0] = packi(wa0.x, wa0.y); f0.u[1] = packi(wa0.z, wa0.w); \
    f0.u[2] = packi(wa1.x, wa1.y); f0.u[3] = packi(wa1.z, wa1.w); \
    f1.u[0] = packi(wb0.x, wb0.y); f1.u[1] = packi(wb0.z, wb0.w); \
    f1.u[2] = packi(wb1.x, wb1.y); f1.u[3] = packi(wb1.z, wb1.w); \
    acc0 = __builtin_amdgcn_mfma_f32_16x16x32_bf16(__builtin_bit_cast(short8, x00##P), f0.s, acc0, 0, 0, 0); \
    acc1 = __builtin_amdgcn_mfma_f32_16x16x32_bf16(__builtin_bit_cast(short8, x10##P), f0.s, acc1, 0, 0, 0); \
    acc0 = __builtin_amdgcn_mfma_f32_16x16x32_bf16(__builtin_bit_cast(short8, x01##P), f1.s, acc0, 0, 0, 0); \
    acc1 = __builtin_amdgcn_mfma_f32_16x16x32_bf16(__builtin_bit_cast(short8, x11##P), f1.s, acc1, 0, 0, 0); }

__global__ __launch_bounds__(512, 4) void main_kernel(
    const u16* __restrict__ xb, const int* __restrict__ wq,
    const float* __restrict__ scale, const float* __restrict__ bias,
    const float* __restrict__ y, const u16* __restrict__ bt,
    float* __restrict__ part) {
    __shared__ int lds[3][4096];  // 3 x 16KB: [64 o-rows][256B] swizzled
    int tid = threadIdx.x, lane = tid & 63, wid = tid >> 6;
    int wm = wid >> 2, wn = wid & 3;
    int col = lane & 15, kg = lane >> 4;
    int bid = blockIdx.x;
    int ot = bid & 63, mt = (bid >> 6) & 1, kq = bid >> 7;
    int o0 = ot * 64;
    int o = o0 + wn * 16 + col;
    int m0 = mt * 64 + wm * 32 + col;
    int k0 = kq * 1024;

    // staging source, inverse-swizzled: LDS[row][b] = G[row][b ^ ((row&7)<<4)]
    int srow = tid >> 4;
    int sb = ((tid & 15) * 16) ^ ((srow & 7) << 4);
    const int* sp1 = wq + (size_t)(o0 + srow) * IN_F + k0 + (sb >> 2);
    const int* sp2 = wq + (size_t)(o0 + 32 + srow) * IN_F + k0 + (sb >> 2);

    const u16* xp0 = xb + (size_t)m0 * IN_F + k0 + kg * 8;
    const u16* xp1 = xp0 + (size_t)16 * IN_F;

    const char* ldsb = (const char*)&lds[0][0];
    int brow = wn * 16 + col;
    int rbyte = brow * 256;
    int bx = (brow & 7) << 4;

    f32x4 acc0 = {0.f, 0.f, 0.f, 0.f}, acc1 = {0.f, 0.f, 0.f, 0.f};
    int4 x00A, x01A, x10A, x11A, x00B, x01B, x10B, x11B;

    // prologue: s0 x0 s1 x1 -> 12 outstanding; steady-state vmcnt(6)
    STAGE(0, 0)
    XLOAD(A, 0)
    STAGE(1, 1)
    XLOAD(B, 1)

    for (int t = 0; t < NT; t += 2) {
        int ta = (t + 2 < NT) ? t + 2 : NT - 1;
        int tb = (t + 3 < NT) ? t + 3 : NT - 1;
        WAITB;                       // retires stage(t)+xload(t)
        STAGE((t + 2) % 3, ta)
        COMPUTE(A, t)
        XLOAD(A, ta)
        WAITB;                       // retires stage(t+1)+xload(t+1)
        STAGE((t + 3) % 3, tb)
        COMPUTE(B, t + 1)
        XLOAD(B, tb)
    }

    float s = scale[o];
    #pragma unroll
    for (int j = 0; j < 4; ++j) { acc0[j] *= s; acc1[j] *= s; }

    if (kq == 0) {  // LoRA + bias folded into slice 0
        const float* yp0 = y + (size_t)m0 * RANK + kg * 8;
        const float* yp1 = yp0 + 16 * RANK;
        const u16* bp = bt + (size_t)o * RANK + kg * 8;
        #pragma unroll
        for (int ks = 0; ks < RANK; ks += 32) {
            f32x4 ya = *(const f32x4*)(yp0 + ks);
            f32x4 yb = *(const f32x4*)(yp0 + ks + 4);
            f32x4 yc = *(const f32x4*)(yp1 + ks);
            f32x4 yd = *(const f32x4*)(yp1 + ks + 4);
            union { u32 u[4]; short8 s; } af0, af1;
            af0.u[0] = packf(ya[0], ya[1]); af0.u[1] = packf(ya[2], ya[3]);
            af0.u[2] = packf(yb[0], yb[1]); af0.u[3] = packf(yb[2], yb[3]);
            af1.u[0] = packf(yc[0], yc[1]); af1.u[1] = packf(yc[2], yc[3]);
            af1.u[2] = packf(yd[0], yd[1]); af1.u[3] = packf(yd[2], yd[3]);
            short8 bfr = *(const short8*)(bp + ks);
            acc0 = __builtin_amdgcn_mfma_f32_16x16x32_bf16(af0.s, bfr, acc0, 0, 0, 0);
            acc1 = __builtin_amdgcn_mfma_f32_16x16x32_bf16(af1.s, bfr, acc1, 0, 0, 0);
        }
        float bv = bias[o];
        #pragma unroll
        for (int j = 0; j < 4; ++j) { acc0[j] += bv; acc1[j] += bv; }
    }

    int rbase = mt * 64 + wm * 32 + kg * 4;
    float* op = part + (size_t)kq * 128 * OUT_F + (size_t)rbase * OUT_F + o;
    #pragma unroll
    for (int j = 0; j < 4; ++j) {
        op[(size_t)j * OUT_F] = acc0[j];
        op[(size_t)(j + 16) * OUT_F] = acc1[j];
    }
}

// ---- reduce_out
__global__ __launch_bounds__(512) void reduce_out_kernel(
    const float* __restrict__ part, float* __restrict__ out) {
    const f32x4* p0 = (const f32x4*)part;
    const f32x4* p1 = p0 + 131072;
    const f32x4* p2 = p1 + 131072;
    const f32x4* p3 = p2 + 131072;
    f32x4* ov = (f32x4*)out;
    int idx = blockIdx.x * 512 + threadIdx.x;
    f32x4 a = p0[idx], b = p1[idx], c = p2[idx], d = p3[idx];
    f32x4 s;
    #pragma unroll
    for (int j = 0; j < 4; ++j) s[j] = (a[j] + b[j]) + (c[j] + d[j]);
    ov[idx] = s;
}

extern "C" void kernel_launch(void* const* d_in, const int* in_sizes, int n_in,
                              void* d_out, int out_size, void* d_ws, size_t ws_size,
                              hipStream_t stream) {
    const float* x = (const float*)d_in[0];
    const int* wq = (const int*)d_in[1];
    const float* scale = (const float*)d_in[2];
    const float* A = (const float*)d_in[3];
    const float* B = (const float*)d_in[4];
    const float* bias = (const float*)d_in[5];
    float* out = (float*)d_out;

    char* ws = (char*)d_ws;
    float* y = (float*)(ws + WS_Y);
    float* yp = (float*)(ws + WS_YP);
    u16* xb = (u16*)(ws + WS_XB);
    u16* bt = (u16*)(ws + WS_BT);
    u16* at = (u16*)(ws + WS_AT);
    float* part = (float*)(ws + WS_PART);

    prep1_kernel<<<640, 512, 0, stream>>>(x, A, B, xb, at, bt);
    prep2_kernel<<<64, 512, 0, stream>>>(xb, at, yp);
    reduce_y_kernel<<<8, 512, 0, stream>>>(yp, y);
    main_kernel<<<512, 512, 0, stream>>>(xb, wq, scale, bias, y, bt, part);
    reduce_out_kernel<<<256, 512, 0, stream>>>(part, out);
}